// Round 5
// baseline (101.723 us; speedup 1.0000x reference)
//
#include <hip/hip_runtime.h>
#include <math.h>

#define D 256
#define Q 256
#define I 2048

__device__ __forceinline__ float wave_sum(float v) {
#pragma unroll
    for (int off = 1; off < 64; off <<= 1)
        v += __shfl_xor(v, off, 64);
    return v;
}

__device__ __forceinline__ float sigmoidf_(float x) {
    return 1.0f / (1.0f + expf(-x));
}

// Y2 layout: [iblk (16)][d (256)][i_in (128)]  -- block-tiled, contiguous per d-row
// grid.x in [0,128): gallery blocks, 16 rows each
// grid.x in [128,192): query prep blocks (4 queries each, one per wave)
__global__ void __launch_bounds__(256)
prep_all(const float* __restrict__ qf,
         const float* __restrict__ qif,
         const float* __restrict__ gal,
         const float* __restrict__ gamma,
         const float* __restrict__ beta,
         const float* __restrict__ mean,
         const float* __restrict__ var,
         float* __restrict__ p,
         float* __restrict__ w,
         float* __restrict__ v2,
         float* __restrict__ Y2,
         float* __restrict__ sq,
         float* __restrict__ ccp) {
    const int t = threadIdx.x;
    const int wv = t >> 6;      // wave id 0..3
    const int l  = t & 63;      // lane

    if (blockIdx.x < 128) {
        // ---- gallery: normalize 16 rows, write tiled-transposed ----
        __shared__ float tile[16][257];
        __shared__ float sinv[16];
        const int i0 = blockIdx.x * 16;
        const float4* g4 = (const float4*)gal;   // row = 64 float4s

#pragma unroll
        for (int c = 0; c < 4; c++) {
            int row = c * 4 + wv;
            float4 r = g4[(size_t)(i0 + row) * 64 + l];
            *(float4*)&tile[row][4 * l] = r;
        }
        __syncthreads();

#pragma unroll
        for (int k = 0; k < 4; k++) {
            int row = k * 4 + wv;
            float4 v = *(const float4*)&tile[row][4 * l];
            float s = wave_sum(v.x * v.x + v.y * v.y + v.z * v.z + v.w * v.w);
            if (l == 0) sinv[row] = 1.0f / fmaxf(sqrtf(s), 1e-12f);
        }
        __syncthreads();

        const int iblk = i0 >> 7;          // 128-item tile index
        const int ioff = i0 & 127;         // offset within tile
        const int col  = l & 15;           // item within our 16 rows
        const int dgrp = l >> 4;           // 0..3
        const float si = sinv[col];
        float* dst = Y2 + (size_t)iblk * (D * 128) + ioff + col;
#pragma unroll
        for (int c = 0; c < 16; c++) {
            int d = c * 16 + wv * 4 + dgrp;
            dst[(size_t)d * 128] = tile[col][d] * si;
        }
    } else {
        // ---- query prep: one query per wave, lane holds d = 4l..4l+3 ----
        const int q = (blockIdx.x - 128) * 4 + wv;
        const float4* qf4  = (const float4*)qf;
        const float4* qif4 = (const float4*)qif;
        const float4* ga4  = (const float4*)gamma;
        const float4* be4  = (const float4*)beta;
        const float4* me4  = (const float4*)mean;
        const float4* va4  = (const float4*)var;

        float4 x = qf4[(size_t)q * 64 + l];
        float nx = wave_sum(x.x * x.x + x.y * x.y + x.z * x.z + x.w * x.w);
        float inx = 1.0f / fmaxf(sqrtf(nx), 1e-12f);
        float g0 = sigmoidf_(x.x * inx * 5.0f);
        float g1 = sigmoidf_(x.y * inx * 5.0f);
        float g2 = sigmoidf_(x.z * inx * 5.0f);
        float g3 = sigmoidf_(x.w * inx * 5.0f);

        float4 y = qif4[(size_t)q * 64 + l];
        float ny = wave_sum(y.x * y.x + y.y * y.y + y.z * y.z + y.w * y.w);
        float iny = 1.0f / fmaxf(sqrtf(ny), 1e-12f);

        float4 gm = ga4[l], bt = be4[l], mn = me4[l], vr = va4[l];
        float is0 = gm.x * rsqrtf(vr.x + 1e-5f);
        float is1 = gm.y * rsqrtf(vr.y + 1e-5f);
        float is2 = gm.z * rsqrtf(vr.z + 1e-5f);
        float is3 = gm.w * rsqrtf(vr.w + 1e-5f);
        float c0 = bt.x - mn.x * is0;
        float c1 = bt.y - mn.y * is1;
        float c2 = bt.z - mn.z * is2;
        float c3 = bt.w - mn.w * is3;
        float a0 = g0 * is0, a1 = g1 * is1, a2 = g2 * is2, a3 = g3 * is3;

        float f0 = y.x * iny * a0 + c0;
        float f1 = y.y * iny * a1 + c1;
        float f2 = y.z * iny * a2 + c2;
        float f3 = y.w * iny * a3 + c3;
        float nf = wave_sum(f0 * f0 + f1 * f1 + f2 * f2 + f3 * f3);
        float inf_ = 1.0f / fmaxf(sqrtf(nf), 1e-12f);
        float u0 = f0 * inf_, u1 = f1 * inf_, u2 = f2 * inf_, u3 = f3 * inf_;

        float4 pw = make_float4(u0 * a0, u1 * a1, u2 * a2, u3 * a3);
        float4 ww = make_float4(a0 * a0, a1 * a1, a2 * a2, a3 * a3);
        float4 vv = make_float4(2.0f * a0 * c0, 2.0f * a1 * c1,
                                2.0f * a2 * c2, 2.0f * a3 * c3);
        ((float4*)p)[(size_t)q * 64 + l]  = pw;
        ((float4*)w)[(size_t)q * 64 + l]  = ww;
        ((float4*)v2)[(size_t)q * 64 + l] = vv;

        float s = wave_sum(u0 * c0 + u1 * c1 + u2 * c2 + u3 * c3);
        if (l == 0) sq[q] = s;

        if (q == 0) {
            float ccs = wave_sum(c0 * c0 + c1 * c1 + c2 * c2 + c3 * c3);
            if (l == 0) *ccp = ccs;
        }
    }
}

// grid = (Q/4, I/128); block = 256 (4 waves). Wave wv: query q0+wv, the
// block's 128 items (2/thread, float2). Explicit 8-deep register pipeline
// keeps 8 loads in flight per wave; 1024 blocks -> 4 waves/SIMD.
// P/W/V reads wave-uniform -> s_load. No LDS, no barriers.
__global__ void __launch_bounds__(256)
main_scores(const float* __restrict__ Y2,
            const float* __restrict__ p,
            const float* __restrict__ w,
            const float* __restrict__ v2,
            const float* __restrict__ sq,
            const float* __restrict__ ccp,
            float* __restrict__ out) {
    const int t = threadIdx.x, wv = t >> 6, lane = t & 63;
    const int q = __builtin_amdgcn_readfirstlane(blockIdx.x * 4 + wv);
    const int iblk = blockIdx.y;

    const float* __restrict__ P = p  + (size_t)q * D;
    const float* __restrict__ W = w  + (size_t)q * D;
    const float* __restrict__ V = v2 + (size_t)q * D;
    // thread's float2 within each 128-float d-row
    const float2* __restrict__ Yb =
        (const float2*)Y2 + (size_t)iblk * (D * 64) + lane;

    float2 a1 = make_float2(0.f, 0.f), a2 = make_float2(0.f, 0.f);

    float2 ybuf[8];
#pragma unroll
    for (int j = 0; j < 8; j++) ybuf[j] = Yb[(size_t)j * 64];

    for (int dc = 0; dc < D; dc += 8) {
        float2 ycur[8];
#pragma unroll
        for (int j = 0; j < 8; j++) ycur[j] = ybuf[j];
        if (dc + 8 < D) {
#pragma unroll
            for (int j = 0; j < 8; j++)
                ybuf[j] = Yb[(size_t)(dc + 8 + j) * 64];
        }
#pragma unroll
        for (int j = 0; j < 8; j++) {
            const float pp = P[dc + j], ww = W[dc + j], vv = V[dc + j];
            const float2 y = ycur[j];
            a1.x += pp * y.x;  a1.y += pp * y.y;
            float t0 = ww * y.x + vv;
            float t1 = ww * y.y + vv;
            a2.x += y.x * t0;  a2.y += y.y * t1;
        }
    }

    const float cc = *ccp;
    const float s = sq[q];
    float2 o;
    o.x = sigmoidf_((a1.x + s) / fmaxf(sqrtf(fmaxf(a2.x + cc, 0.f)), 1e-12f));
    o.y = sigmoidf_((a1.y + s) / fmaxf(sqrtf(fmaxf(a2.y + cc, 0.f)), 1e-12f));
    *(float2*)&out[(size_t)q * I + iblk * 128 + lane * 2] = o;
}

extern "C" void kernel_launch(void* const* d_in, const int* in_sizes, int n_in,
                              void* d_out, int out_size, void* d_ws, size_t ws_size,
                              hipStream_t stream) {
    const float* qf    = (const float*)d_in[0]; // [Q,D]
    const float* qif   = (const float*)d_in[1]; // [Q,D]
    const float* gal   = (const float*)d_in[2]; // [I,D]
    const float* gamma = (const float*)d_in[3];
    const float* beta  = (const float*)d_in[4];
    const float* mean  = (const float*)d_in[5];
    const float* var   = (const float*)d_in[6];
    float* out = (float*)d_out;                 // [Q,I]

    float* ws  = (float*)d_ws;
    float* p   = ws;                        // Q*D
    float* w   = p  + Q * D;                // Q*D
    float* v2  = w  + Q * D;                // Q*D
    float* Y2  = v2 + Q * D;                // D*I (tiled [16][256][128])
    float* sq  = Y2 + (size_t)D * I;        // Q
    float* cc  = sq + Q;                    // 1

    prep_all<<<192, 256, 0, stream>>>(qf, qif, gal, gamma, beta, mean, var,
                                      p, w, v2, Y2, sq, cc);
    main_scores<<<dim3(Q / 4, I / 128), 256, 0, stream>>>(Y2, p, w, v2, sq, cc, out);
}

// Round 6
// 97.271 us; speedup vs baseline: 1.0458x; 1.0458x over previous
//
#include <hip/hip_runtime.h>
#include <math.h>

#define D 256
#define Q 256
#define I 2048

__device__ __forceinline__ float wave_sum(float v) {
#pragma unroll
    for (int off = 1; off < 64; off <<= 1)
        v += __shfl_xor(v, off, 64);
    return v;
}

__device__ __forceinline__ float sigmoidf_(float x) {
    return 1.0f / (1.0f + expf(-x));
}

// Y3 layout: [iblk (8)][d (256)][i_in (256)] -- 256-item tiles, 1KB d-rows
// grid.x in [0,64): gallery transpose+normalize blocks (32 rows each)
// grid.x in [64,128): query prep blocks (4 queries each, one per wave)
__global__ void __launch_bounds__(256)
prep_all(const float* __restrict__ qf,
         const float* __restrict__ qif,
         const float* __restrict__ gal,
         const float* __restrict__ gamma,
         const float* __restrict__ beta,
         const float* __restrict__ mean,
         const float* __restrict__ var,
         float* __restrict__ p,
         float* __restrict__ w,
         float* __restrict__ v2,
         float* __restrict__ Y3,
         float* __restrict__ sq,
         float* __restrict__ ccp) {
    const int t = threadIdx.x;
    const int wv = t >> 6;      // wave id 0..3
    const int l  = t & 63;      // lane

    if (blockIdx.x < 64) {
        // ---- gallery: normalize 32 rows, write tiled-transposed ----
        __shared__ float tile[32][257];   // +1 pad breaks bank conflicts
        __shared__ float sinv[32];
        const int i0 = blockIdx.x * 32;
        const float4* g4 = (const float4*)gal;   // row = 64 float4s

#pragma unroll
        for (int c = 0; c < 8; c++) {
            int row = c * 4 + wv;
            float4 r = g4[(size_t)(i0 + row) * 64 + l];
            *(float4*)&tile[row][4 * l] = r;
        }
        __syncthreads();

#pragma unroll
        for (int k = 0; k < 8; k++) {
            int row = k * 4 + wv;
            float4 v = *(const float4*)&tile[row][4 * l];
            float s = wave_sum(v.x * v.x + v.y * v.y + v.z * v.z + v.w * v.w);
            if (l == 0) sinv[row] = 1.0f / fmaxf(sqrtf(s), 1e-12f);
        }
        __syncthreads();

        const int iblk = i0 >> 8;          // 256-item tile index
        const int ioff = i0 & 255;         // offset within tile
        const int half = l >> 5, col = l & 31;
        const float si = sinv[col];
        float* dst = Y3 + (size_t)iblk * (D * 256) + ioff + col;
#pragma unroll
        for (int c = 0; c < 32; c++) {
            int d = c * 8 + wv * 2 + half;
            dst[(size_t)d * 256] = tile[col][d] * si;
        }
    } else {
        // ---- query prep: one query per wave, lane holds d = 4l..4l+3 ----
        const int q = (blockIdx.x - 64) * 4 + wv;
        const float4* qf4  = (const float4*)qf;
        const float4* qif4 = (const float4*)qif;
        const float4* ga4  = (const float4*)gamma;
        const float4* be4  = (const float4*)beta;
        const float4* me4  = (const float4*)mean;
        const float4* va4  = (const float4*)var;

        float4 x = qf4[(size_t)q * 64 + l];
        float nx = wave_sum(x.x * x.x + x.y * x.y + x.z * x.z + x.w * x.w);
        float inx = 1.0f / fmaxf(sqrtf(nx), 1e-12f);
        float g0 = sigmoidf_(x.x * inx * 5.0f);
        float g1 = sigmoidf_(x.y * inx * 5.0f);
        float g2 = sigmoidf_(x.z * inx * 5.0f);
        float g3 = sigmoidf_(x.w * inx * 5.0f);

        float4 y = qif4[(size_t)q * 64 + l];
        float ny = wave_sum(y.x * y.x + y.y * y.y + y.z * y.z + y.w * y.w);
        float iny = 1.0f / fmaxf(sqrtf(ny), 1e-12f);

        float4 gm = ga4[l], bt = be4[l], mn = me4[l], vr = va4[l];
        float is0 = gm.x * rsqrtf(vr.x + 1e-5f);
        float is1 = gm.y * rsqrtf(vr.y + 1e-5f);
        float is2 = gm.z * rsqrtf(vr.z + 1e-5f);
        float is3 = gm.w * rsqrtf(vr.w + 1e-5f);
        float c0 = bt.x - mn.x * is0;
        float c1 = bt.y - mn.y * is1;
        float c2 = bt.z - mn.z * is2;
        float c3 = bt.w - mn.w * is3;
        float a0 = g0 * is0, a1 = g1 * is1, a2 = g2 * is2, a3 = g3 * is3;

        float f0 = y.x * iny * a0 + c0;
        float f1 = y.y * iny * a1 + c1;
        float f2 = y.z * iny * a2 + c2;
        float f3 = y.w * iny * a3 + c3;
        float nf = wave_sum(f0 * f0 + f1 * f1 + f2 * f2 + f3 * f3);
        float inf_ = 1.0f / fmaxf(sqrtf(nf), 1e-12f);
        float u0 = f0 * inf_, u1 = f1 * inf_, u2 = f2 * inf_, u3 = f3 * inf_;

        float4 pw = make_float4(u0 * a0, u1 * a1, u2 * a2, u3 * a3);
        float4 ww = make_float4(a0 * a0, a1 * a1, a2 * a2, a3 * a3);
        float4 vv = make_float4(2.0f * a0 * c0, 2.0f * a1 * c1,
                                2.0f * a2 * c2, 2.0f * a3 * c3);
        ((float4*)p)[(size_t)q * 64 + l]  = pw;
        ((float4*)w)[(size_t)q * 64 + l]  = ww;
        ((float4*)v2)[(size_t)q * 64 + l] = vv;

        float s = wave_sum(u0 * c0 + u1 * c1 + u2 * c2 + u3 * c3);
        if (l == 0) sq[q] = s;

        if (q == 0) {
            float ccs = wave_sum(c0 * c0 + c1 * c1 + c2 * c2 + c3 * c3);
            if (l == 0) *ccp = ccs;
        }
    }
}

// acc1 += P*y ; t = W*y + V ; acc2 += y*t   (3 FMA per element)
#define ACC_STEP(yv, P_, W_, V_)                 \
    {                                            \
        a1.x += (P_) * yv.x;                     \
        a1.y += (P_) * yv.y;                     \
        a1.z += (P_) * yv.z;                     \
        a1.w += (P_) * yv.w;                     \
        float t0 = (W_) * yv.x + (V_);           \
        float t1 = (W_) * yv.y + (V_);           \
        float t2 = (W_) * yv.z + (V_);           \
        float t3 = (W_) * yv.w + (V_);           \
        a2.x += yv.x * t0;                       \
        a2.y += yv.y * t1;                       \
        a2.z += yv.z * t2;                       \
        a2.w += yv.w * t3;                       \
    }

// grid = (Q/4, I/256); block = 256 (4 waves). Wave = 1 query x 256 items
// (4 items/thread, float4, all 4 waves read the same Y3 tile -> L1 reuse).
// Tiled Y3 rows (1KB stride) give base+immediate addressing; depth-2
// register prefetch keeps 8 float4 loads in flight per thread.
// P/W/V reads wave-uniform -> scalar loads. No LDS, no barriers.
__global__ void __launch_bounds__(256)
main_scores(const float* __restrict__ Y3,
            const float* __restrict__ p,
            const float* __restrict__ w,
            const float* __restrict__ v2,
            const float* __restrict__ sq,
            const float* __restrict__ ccp,
            float* __restrict__ out) {
    const int t = threadIdx.x, wv = t >> 6, lane = t & 63;
    const int q = __builtin_amdgcn_readfirstlane(blockIdx.x * 4 + wv);
    const float4* __restrict__ P = (const float4*)(p  + (size_t)q * D);
    const float4* __restrict__ W = (const float4*)(w  + (size_t)q * D);
    const float4* __restrict__ V = (const float4*)(v2 + (size_t)q * D);
    const float* __restrict__ Yb =
        Y3 + (size_t)blockIdx.y * (D * 256) + lane * 4;   // row d at +d*256

    float4 a1 = make_float4(0.f, 0.f, 0.f, 0.f);
    float4 a2 = make_float4(0.f, 0.f, 0.f, 0.f);

    // chunk dc covers d = 4dc..4dc+3 (4 rows); depth-2 prefetch buffers
    float4 buf[2][4];
#pragma unroll
    for (int c = 0; c < 2; c++)
#pragma unroll
        for (int j = 0; j < 4; j++)
            buf[c][j] = *(const float4*)&Yb[(size_t)(c * 4 + j) * 256];

#pragma unroll 2
    for (int dc = 0; dc < 64; ++dc) {
        float4 cur0 = buf[dc & 1][0];
        float4 cur1 = buf[dc & 1][1];
        float4 cur2 = buf[dc & 1][2];
        float4 cur3 = buf[dc & 1][3];
        if (dc + 2 < 64) {
#pragma unroll
            for (int j = 0; j < 4; j++)
                buf[dc & 1][j] =
                    *(const float4*)&Yb[(size_t)((dc + 2) * 4 + j) * 256];
        }
        float4 pp = P[dc], ww = W[dc], vv = V[dc];
        ACC_STEP(cur0, pp.x, ww.x, vv.x);
        ACC_STEP(cur1, pp.y, ww.y, vv.y);
        ACC_STEP(cur2, pp.z, ww.z, vv.z);
        ACC_STEP(cur3, pp.w, ww.w, vv.w);
    }

    const float s = sq[q];
    const float cc = *ccp;
    float4 o;
    o.x = sigmoidf_((a1.x + s) / fmaxf(sqrtf(fmaxf(a2.x + cc, 0.f)), 1e-12f));
    o.y = sigmoidf_((a1.y + s) / fmaxf(sqrtf(fmaxf(a2.y + cc, 0.f)), 1e-12f));
    o.z = sigmoidf_((a1.z + s) / fmaxf(sqrtf(fmaxf(a2.z + cc, 0.f)), 1e-12f));
    o.w = sigmoidf_((a1.w + s) / fmaxf(sqrtf(fmaxf(a2.w + cc, 0.f)), 1e-12f));
    *(float4*)&out[(size_t)q * I + blockIdx.y * 256 + lane * 4] = o;
}

extern "C" void kernel_launch(void* const* d_in, const int* in_sizes, int n_in,
                              void* d_out, int out_size, void* d_ws, size_t ws_size,
                              hipStream_t stream) {
    const float* qf    = (const float*)d_in[0]; // [Q,D]
    const float* qif   = (const float*)d_in[1]; // [Q,D]
    const float* gal   = (const float*)d_in[2]; // [I,D]
    const float* gamma = (const float*)d_in[3];
    const float* beta  = (const float*)d_in[4];
    const float* mean  = (const float*)d_in[5];
    const float* var   = (const float*)d_in[6];
    float* out = (float*)d_out;                 // [Q,I]

    float* ws  = (float*)d_ws;
    float* p   = ws;                        // Q*D
    float* w   = p  + Q * D;                // Q*D
    float* v2  = w  + Q * D;                // Q*D
    float* Y3  = v2 + Q * D;                // D*I (tiled [8][256][256])
    float* sq  = Y3 + (size_t)D * I;        // Q
    float* cc  = sq + Q;                    // 1

    prep_all<<<128, 256, 0, stream>>>(qf, qif, gal, gamma, beta, mean, var,
                                      p, w, v2, Y3, sq, cc);
    main_scores<<<dim3(Q / 4, I / 256), 256, 0, stream>>>(Y3, p, w, v2, sq, cc, out);
}

// Round 7
// 78.253 us; speedup vs baseline: 1.2999x; 1.2430x over previous
//
#include <hip/hip_runtime.h>
#include <math.h>

#define D 256
#define Q 256
#define I 2048

typedef __attribute__((ext_vector_type(8))) short short8;
typedef __attribute__((ext_vector_type(4))) float floatx4;

__device__ __forceinline__ float wave_sum(float v) {
#pragma unroll
    for (int off = 1; off < 64; off <<= 1)
        v += __shfl_xor(v, off, 64);
    return v;
}

__device__ __forceinline__ float sigmoidf_(float x) {
    return 1.0f / (1.0f + expf(-x));
}

// fp32 -> bf16 round-to-nearest-even
__device__ __forceinline__ unsigned short f2bf(float f) {
    unsigned u = __float_as_uint(f);
    u += 0x7FFFu + ((u >> 16) & 1u);
    return (unsigned short)(u >> 16);
}

// grid.x in [0,64): gallery blocks (32 rows each): normalize, write bf16 Y and Y^2
//                   row-major [i][d] -- NO transpose needed for MFMA path.
// grid.x in [64,128): query prep blocks (4 queries each, one per wave):
//                   write bf16 P/W/V row-major [q][d] + fp32 sq[q], cc.
__global__ void __launch_bounds__(256)
prep_all(const float* __restrict__ qf,
         const float* __restrict__ qif,
         const float* __restrict__ gal,
         const float* __restrict__ gamma,
         const float* __restrict__ beta,
         const float* __restrict__ mean,
         const float* __restrict__ var,
         unsigned short* __restrict__ PB,
         unsigned short* __restrict__ WB,
         unsigned short* __restrict__ VB,
         unsigned short* __restrict__ YB,
         unsigned short* __restrict__ Y2B,
         float* __restrict__ sq,
         float* __restrict__ ccp) {
    const int t = threadIdx.x;
    const int wv = t >> 6;      // wave id 0..3
    const int l  = t & 63;      // lane

    if (blockIdx.x < 64) {
        // ---- gallery: wave handles 8 rows; lane l holds d = 4l..4l+3 ----
        const int i0 = blockIdx.x * 32;
        const float4* g4 = (const float4*)gal;   // row = 64 float4s
#pragma unroll
        for (int r = 0; r < 8; r++) {
            const int row = i0 + wv * 8 + r;
            float4 x = g4[(size_t)row * 64 + l];
            float s = wave_sum(x.x * x.x + x.y * x.y + x.z * x.z + x.w * x.w);
            float inv = 1.0f / fmaxf(sqrtf(s), 1e-12f);
            float y0 = x.x * inv, y1 = x.y * inv, y2 = x.z * inv, y3 = x.w * inv;
            *(ushort4*)&YB[(size_t)row * D + 4 * l] =
                make_ushort4(f2bf(y0), f2bf(y1), f2bf(y2), f2bf(y3));
            *(ushort4*)&Y2B[(size_t)row * D + 4 * l] =
                make_ushort4(f2bf(y0 * y0), f2bf(y1 * y1),
                             f2bf(y2 * y2), f2bf(y3 * y3));
        }
    } else {
        // ---- query prep: one query per wave, lane holds d = 4l..4l+3 ----
        const int q = (blockIdx.x - 64) * 4 + wv;
        const float4* qf4  = (const float4*)qf;
        const float4* qif4 = (const float4*)qif;
        const float4* ga4  = (const float4*)gamma;
        const float4* be4  = (const float4*)beta;
        const float4* me4  = (const float4*)mean;
        const float4* va4  = (const float4*)var;

        float4 x = qf4[(size_t)q * 64 + l];
        float nx = wave_sum(x.x * x.x + x.y * x.y + x.z * x.z + x.w * x.w);
        float inx = 1.0f / fmaxf(sqrtf(nx), 1e-12f);
        float g0 = sigmoidf_(x.x * inx * 5.0f);
        float g1 = sigmoidf_(x.y * inx * 5.0f);
        float g2 = sigmoidf_(x.z * inx * 5.0f);
        float g3 = sigmoidf_(x.w * inx * 5.0f);

        float4 y = qif4[(size_t)q * 64 + l];
        float ny = wave_sum(y.x * y.x + y.y * y.y + y.z * y.z + y.w * y.w);
        float iny = 1.0f / fmaxf(sqrtf(ny), 1e-12f);

        float4 gm = ga4[l], bt = be4[l], mn = me4[l], vr = va4[l];
        float is0 = gm.x * rsqrtf(vr.x + 1e-5f);
        float is1 = gm.y * rsqrtf(vr.y + 1e-5f);
        float is2 = gm.z * rsqrtf(vr.z + 1e-5f);
        float is3 = gm.w * rsqrtf(vr.w + 1e-5f);
        float c0 = bt.x - mn.x * is0;
        float c1 = bt.y - mn.y * is1;
        float c2 = bt.z - mn.z * is2;
        float c3 = bt.w - mn.w * is3;
        float a0 = g0 * is0, a1 = g1 * is1, a2 = g2 * is2, a3 = g3 * is3;

        float f0 = y.x * iny * a0 + c0;
        float f1 = y.y * iny * a1 + c1;
        float f2 = y.z * iny * a2 + c2;
        float f3 = y.w * iny * a3 + c3;
        float nf = wave_sum(f0 * f0 + f1 * f1 + f2 * f2 + f3 * f3);
        float inf_ = 1.0f / fmaxf(sqrtf(nf), 1e-12f);
        float u0 = f0 * inf_, u1 = f1 * inf_, u2 = f2 * inf_, u3 = f3 * inf_;

        *(ushort4*)&PB[(size_t)q * D + 4 * l] =
            make_ushort4(f2bf(u0 * a0), f2bf(u1 * a1),
                         f2bf(u2 * a2), f2bf(u3 * a3));
        *(ushort4*)&WB[(size_t)q * D + 4 * l] =
            make_ushort4(f2bf(a0 * a0), f2bf(a1 * a1),
                         f2bf(a2 * a2), f2bf(a3 * a3));
        *(ushort4*)&VB[(size_t)q * D + 4 * l] =
            make_ushort4(f2bf(2.0f * a0 * c0), f2bf(2.0f * a1 * c1),
                         f2bf(2.0f * a2 * c2), f2bf(2.0f * a3 * c3));

        float s = wave_sum(u0 * c0 + u1 * c1 + u2 * c2 + u3 * c3);
        if (l == 0) sq[q] = s;

        if (q == 0) {
            float ccs = wave_sum(c0 * c0 + c1 * c1 + c2 * c2 + c3 * c3);
            if (l == 0) *ccp = ccs;
        }
    }
}

// MFMA main. out[i,q]-tiles via mfma_f32_16x16x32_bf16:
//   acc1[i,q] = sum_k Y[i,k]  * P[q,k]
//   acc2[i,q] = sum_k Y2[i,k] * W[q,k] + Y[i,k] * V[q,k]
// A-frag: lane holds A[m=lane&15][k=quad*8+j] -> 16B contiguous from row-major Y.
// B-frag: lane holds B[k=quad*8+j][n=lane&15] = P[n][k] -> 16B contiguous rows.
// C/D:    col(q)=lane&15, row(i)=quad*4+reg.
// grid = (Q/64, I/32); block = 256 (4 waves). Wave: 16 q x 32 i; B-frags for
// the full K=256 hoisted in registers (96 VGPRs). No LDS, no barriers.
__global__ void __launch_bounds__(256)
main_scores(const unsigned short* __restrict__ YB,
            const unsigned short* __restrict__ Y2B,
            const unsigned short* __restrict__ PB,
            const unsigned short* __restrict__ WB,
            const unsigned short* __restrict__ VB,
            const float* __restrict__ sq,
            const float* __restrict__ ccp,
            float* __restrict__ out) {
    const int t = threadIdx.x, wv = t >> 6, l = t & 63;
    const int lm = l & 15, quad = l >> 4;
    const int q0 = blockIdx.x * 64 + wv * 16;
    const int qr = q0 + lm;                 // lane's q row (B operand + output col)
    const int koff = quad * 8;

    short8 bp[8], bw[8], bv[8];
#pragma unroll
    for (int ks = 0; ks < 8; ks++) {
        const size_t o = (size_t)qr * D + ks * 32 + koff;
        bp[ks] = *(const short8*)&PB[o];
        bw[ks] = *(const short8*)&WB[o];
        bv[ks] = *(const short8*)&VB[o];
    }
    const float sqv = sq[qr];
    const float ccv = *ccp;

#pragma unroll
    for (int it = 0; it < 2; it++) {
        const int i_t = blockIdx.y * 32 + it * 16;
        const int ir = i_t + lm;            // lane's A row (i)
        floatx4 acc1 = {0.f, 0.f, 0.f, 0.f};
        floatx4 acc2 = {0.f, 0.f, 0.f, 0.f};
#pragma unroll
        for (int ks = 0; ks < 8; ks++) {
            const size_t o = (size_t)ir * D + ks * 32 + koff;
            short8 ay  = *(const short8*)&YB[o];
            short8 ay2 = *(const short8*)&Y2B[o];
            acc1 = __builtin_amdgcn_mfma_f32_16x16x32_bf16(ay,  bp[ks], acc1, 0, 0, 0);
            acc2 = __builtin_amdgcn_mfma_f32_16x16x32_bf16(ay2, bw[ks], acc2, 0, 0, 0);
            acc2 = __builtin_amdgcn_mfma_f32_16x16x32_bf16(ay,  bv[ks], acc2, 0, 0, 0);
        }
        float4 o4;
        float* po = &o4.x;
#pragma unroll
        for (int r = 0; r < 4; r++) {
            float nrm = fmaxf(sqrtf(fmaxf(acc2[r] + ccv, 0.f)), 1e-12f);
            po[r] = sigmoidf_((acc1[r] + sqv) / nrm);
        }
        // lane writes out[qr][i_t + quad*4 .. +3] (contiguous float4)
        *(float4*)&out[(size_t)qr * I + i_t + quad * 4] = o4;
    }
}

extern "C" void kernel_launch(void* const* d_in, const int* in_sizes, int n_in,
                              void* d_out, int out_size, void* d_ws, size_t ws_size,
                              hipStream_t stream) {
    const float* qf    = (const float*)d_in[0]; // [Q,D]
    const float* qif   = (const float*)d_in[1]; // [Q,D]
    const float* gal   = (const float*)d_in[2]; // [I,D]
    const float* gamma = (const float*)d_in[3];
    const float* beta  = (const float*)d_in[4];
    const float* mean  = (const float*)d_in[5];
    const float* var   = (const float*)d_in[6];
    float* out = (float*)d_out;                 // [Q,I]

    char* base = (char*)d_ws;
    float* sq = (float*)base;                               // Q floats (1 KB)
    float* cc = (float*)(base + 1024);                      // 1 float
    unsigned short* PB  = (unsigned short*)(base + 2048);   // Q*D bf16
    unsigned short* WB  = PB + (size_t)Q * D;
    unsigned short* VB  = WB + (size_t)Q * D;
    unsigned short* YB  = VB + (size_t)Q * D;               // I*D bf16
    unsigned short* Y2B = YB + (size_t)I * D;

    prep_all<<<128, 256, 0, stream>>>(qf, qif, gal, gamma, beta, mean, var,
                                      PB, WB, VB, YB, Y2B, sq, cc);
    main_scores<<<dim3(Q / 64, I / 32), 256, 0, stream>>>(YB, Y2B, PB, WB, VB,
                                                          sq, cc, out);
}